// Round 9
// baseline (1925.558 us; speedup 1.0000x reference)
//
#include <hip/hip_runtime.h>
#include <math.h>

#define B_    16
#define T_    4096
#define C_    256
#define CIN1  80
#define EMB   128
#define TP    341
#define NPOS  (B_*TP)      // 5456
#define NQ_   8
#define KCB   256
#define BN_EPS 1e-5

// ---------------- prep kernels ----------------
__global__ __launch_bounds__(256) void prep_common(
    const float* __restrict__ wd,
    const float* __restrict__ b1, const float* __restrict__ g1,
    const float* __restrict__ be1, const float* __restrict__ m1,
    const float* __restrict__ v1,
    const float* __restrict__ b2, const float* __restrict__ g2,
    const float* __restrict__ be2, const float* __restrict__ m2,
    const float* __restrict__ v2,
    float* __restrict__ wdt,
    double* __restrict__ a1, double* __restrict__ bt1,
    double* __restrict__ a2, double* __restrict__ bt2)
{
    int j = blockIdx.x * 256 + threadIdx.x;
    if (j < 256*24*128) wdt[j] = wd[(size_t)(j & 127) * 6144 + (j >> 7)];
    if (j < 256) {
        double inv1 = 1.0 / sqrt((double)v1[j] + BN_EPS);
        double s1 = (double)g1[j] * inv1;
        a1[j]  = s1;
        bt1[j] = ((double)b1[j] - (double)m1[j]) * s1 + (double)be1[j];
        double inv2 = 1.0 / sqrt((double)v2[j] + BN_EPS);
        double s2 = (double)g2[j] * inv2;
        a2[j]  = s2;
        bt2[j] = ((double)b2[j] - (double)m2[j]) * s2 + (double)be2[j];
    }
}

// transposed weight tables: [(ci*5+k)*256 + co]
__global__ __launch_bounds__(256) void prep_wf64(
    const float* __restrict__ w1, const float* __restrict__ w2,
    double* __restrict__ w1td, double* __restrict__ w2td)
{
    int j = blockIdx.x * 256 + threadIdx.x;
    if (j < 256*5*256) w2td[j] = (double)w2[(size_t)(j & 255) * 1280 + (j >> 8)];
    if (j < 80*5*256)  w1td[j] = (double)w1[(size_t)(j & 255) * 400 + (j >> 8)];
}
__global__ __launch_bounds__(256) void prep_wf32(
    const float* __restrict__ w1, const float* __restrict__ w2,
    float* __restrict__ w1tf, float* __restrict__ w2tf)
{
    int j = blockIdx.x * 256 + threadIdx.x;
    if (j < 256*5*256) w2tf[j] = w2[(size_t)(j & 255) * 1280 + (j >> 8)];
    if (j < 80*5*256)  w1tf[j] = w1[(size_t)(j & 255) * 400 + (j >> 8)];
}

// bank swizzle on 16B granularity (convd only)
__device__ __forceinline__ int swz_pair(int col) {        // col even (f64 idx)
    int bw = col >> 1;
    return ((bw ^ ((bw >> 3) & 7)) << 1);
}
__device__ __forceinline__ int swz_scalar(int col) {      // any f64 idx
    int bw = col >> 1;
    return (((bw ^ ((bw >> 3) & 7)) << 1) | (col & 1));
}

// ---------------- f64 conv(k=5,pad=2) + BN + ReLU, v10: LDS-free ----------------
// Wave = 64 lanes over t (2 t each -> 128 t); each wave owns a 16-co strip.
// w reads are wave-uniform (scalar pipe); x reads straight from global (L1).
// grid: (4 co-tiles of 64, 32 t-tiles of 128, nb). 256 thr = 4 waves.
template<int CIN, typename Tin, typename WT>
__global__ __launch_bounds__(256, 4) void conv5_v10(
    const Tin* __restrict__ in,       // [nb][CIN][T]
    const WT* __restrict__ wt,        // [(ci*5+k)][256]
    const double* __restrict__ alpha, const double* __restrict__ beta,
    double* __restrict__ out)         // [nb][256][T]
{
    const int b  = blockIdx.z;
    const int t0 = blockIdx.y * 128;
    const int wv = __builtin_amdgcn_readfirstlane((int)(threadIdx.x >> 6));
    const int lane = threadIdx.x & 63;
    const int co0 = blockIdx.x * 64 + wv * 16;
    const int t = t0 + lane * 2;

    double acc[16][2];
    #pragma unroll
    for (int c = 0; c < 16; ++c) { acc[c][0] = 0.0; acc[c][1] = 0.0; }

    const Tin* xb = in + (size_t)b * CIN * T_;
    const bool interior = (t0 != 0) && (t0 + 130 <= T_);

    for (int ci = 0; ci < CIN; ++ci) {
        double xv[6];
        const Tin* xp = xb + (size_t)ci * T_ + (t - 2);
        if (interior) {
            #pragma unroll
            for (int d = 0; d < 6; ++d) xv[d] = (double)xp[d];
        } else {
            #pragma unroll
            for (int d = 0; d < 6; ++d) {
                int tt = t - 2 + d;
                xv[d] = (tt >= 0 && tt < T_) ? (double)xp[d] : 0.0;
            }
        }
        const WT* wrow = wt + (size_t)ci * 5 * 256 + co0;
        #pragma unroll
        for (int k = 0; k < 5; ++k) {
            #pragma unroll
            for (int c = 0; c < 16; ++c) {
                double w = (double)wrow[k * 256 + c];
                acc[c][0] = fma(w, xv[k],     acc[c][0]);
                acc[c][1] = fma(w, xv[k + 1], acc[c][1]);
            }
        }
    }

    #pragma unroll
    for (int c = 0; c < 16; ++c) {
        int co = co0 + c;
        double a = alpha[co], bt = beta[co];
        double y0 = fma(acc[c][0], a, bt);
        double y1 = fma(acc[c][1], a, bt);
        double2 o;
        o.x = y0 > 0.0 ? y0 : 0.0;
        o.y = y1 > 0.0 ? y1 : 0.0;
        *(double2*)&out[((size_t)(b * C_ + co)) * T_ + t] = o;
    }
}

// ---------------- f64 downsample conv v7: k=24, stride=12, pad=6 ----------------
// block: 128 co x 128 tp. 256 thr: tcol=tid&15 (8 tp), crow=tid>>4 (8 co).
// x staged kpos-major + swizzle -> conflict-free. chunk = 1 ci.
__global__ __launch_bounds__(256, 2) void convd_f64_v7(
    const double* __restrict__ x2,    // [nb][256][T]
    const float* __restrict__ wdt,    // f32 [(ci*24+k)][128]
    double* __restrict__ parts,       // [nsplit][nb][128][341]
    int nb, int nsplit, int cis)
{
    const int bz  = blockIdx.z;
    const int s   = bz % nsplit;
    const int b   = bz / nsplit;
    const int tp0 = blockIdx.x * 128;
    const int tid = threadIdx.x;
    const int tcol = tid & 15;
    const int crow = tid >> 4;

    __shared__ __align__(16) double xs2[24][132]; // kpos-major, swizzled cols
    __shared__ __align__(16) double wsh[24][128];

    double acc[8][8];
    #pragma unroll
    for (int i = 0; i < 8; ++i)
        #pragma unroll
        for (int j = 0; j < 8; ++j) acc[i][j] = 0.0;

    const int tbase = tp0 * 12 - 6;
    const int ci_begin = s * cis;

    for (int c = ci_begin; c < ci_begin + cis; ++c) {
        for (int i = tid; i < 1548; i += 256) {
            int t = tbase + i;
            double v = (t >= 0 && t < T_)
                ? x2[((size_t)(b * 256 + c)) * T_ + t] : 0.0;
            int tp = (i * 43691) >> 19;           // i/12
            int kp = i - tp * 12;
            xs2[kp][swz_scalar(tp)] = v;
            if (tp >= 1) xs2[kp + 12][swz_scalar(tp - 1)] = v;
        }
        for (int i = tid; i < 24 * 128; i += 256) {
            int r = i >> 7, cc = i & 127;
            wsh[r][cc] = (double)wdt[((size_t)c * 24 + r) * 128 + cc];
        }
        __syncthreads();

        #pragma unroll 4
        for (int k = 0; k < 24; ++k) {
            double wv[8];
            #pragma unroll
            for (int m = 0; m < 4; ++m) {
                double2 w2v = *(const double2*)&wsh[k][crow * 8 + 2 * m];
                wv[2 * m] = w2v.x; wv[2 * m + 1] = w2v.y;
            }
            #pragma unroll
            for (int jp = 0; jp < 4; ++jp) {
                double2 xp = *(const double2*)&xs2[k][swz_pair(tcol * 2 + 32 * jp)];
                #pragma unroll
                for (int i = 0; i < 8; ++i) {
                    acc[i][jp * 2]     = fma(wv[i], xp.x, acc[i][jp * 2]);
                    acc[i][jp * 2 + 1] = fma(wv[i], xp.y, acc[i][jp * 2 + 1]);
                }
            }
        }
        __syncthreads();
    }

    #pragma unroll
    for (int i = 0; i < 8; ++i) {
        int co = crow * 8 + i;
        #pragma unroll
        for (int jp = 0; jp < 4; ++jp) {
            #pragma unroll
            for (int e = 0; e < 2; ++e) {
                int tp = tp0 + tcol * 2 + 32 * jp + e;
                if (tp < TP)
                    parts[(((size_t)s * nb + b) * EMB + co) * TP + tp] = acc[i][jp * 2 + e];
            }
        }
    }
}

// ---------------- combine partials + bias -> parts[0] (=e, f64) + e_out (f32) ----
__global__ __launch_bounds__(256) void convd_combine(
    double* __restrict__ parts,       // [nsplit][nb][128][341]; writes slot 0
    const float* __restrict__ bd,
    float* __restrict__ e_out,        // [16][128][341]
    int nb, int b_off, int nsplit)
{
    int idx = blockIdx.x * 256 + threadIdx.x;
    int total = nb * EMB * TP;
    if (idx >= total) return;
    int rem = idx % (EMB * TP);
    int co = rem / TP;
    size_t stride = (size_t)nb * EMB * TP;
    double y = 0.0;
    for (int s = 0; s < nsplit; ++s)     // ascending s: deterministic
        y += parts[(size_t)s * stride + idx];
    y += (double)bd[co];
    parts[idx] = y;                      // in-place e (f64)
    e_out[(size_t)b_off * EMB * TP + idx] = (float)y;
}

// ---------------- f64 1x1 projection (per group) ----------------
__global__ __launch_bounds__(128) void zproj_f64(
    const double* __restrict__ ed,    // [nb][128][341]  (= parts[0])
    const float* __restrict__ wp,     // [16][128] f32
    const float* __restrict__ bp,     // [16] f32
    double* __restrict__ z)           // [nb][341][16]
{
    const int b = blockIdx.y;
    const int t = blockIdx.x * 128 + threadIdx.x;
    __shared__ double wps[16][128];
    for (int i = threadIdx.x; i < 16 * 128; i += 128)
        wps[i >> 7][i & 127] = (double)wp[i];
    __syncthreads();
    if (t >= TP) return;
    double acc[16];
    #pragma unroll
    for (int v = 0; v < 16; ++v) acc[v] = (double)bp[v];
    for (int co = 0; co < 128; ++co) {
        double x = ed[((size_t)(b * EMB + co)) * TP + t];
        #pragma unroll
        for (int v = 0; v < 16; ++v) acc[v] = fma(x, wps[v][co], acc[v]);
    }
    #pragma unroll
    for (int v = 0; v < 16; ++v)
        z[((size_t)(b * TP + t)) * 16 + v] = acc[v];
}

// ---------------- RVQ: f64 distances, wave-shuffle argmin ----------------
__global__ __launch_bounds__(256) void rvq_f64_v2(
    const double* __restrict__ z,     // [NPOS][16]
    const float* __restrict__ cb,     // [8][256][16]
    float* __restrict__ out_idx)      // [8][NPOS] as float
{
    const int pos = blockIdx.x;
    const int tid = threadIdx.x;
    const int lane = tid & 63;
    const int wv = tid >> 6;

    __shared__ double r[16];
    __shared__ double wd_s[4];
    __shared__ int wi_s[4];
    __shared__ int best_s;

    if (tid < 16) r[tid] = z[(size_t)pos * 16 + tid];
    __syncthreads();

    for (int q = 0; q < NQ_; ++q) {
        const float* c = cb + ((size_t)(q * KCB) + tid) * 16;
        double d = 0.0;
        #pragma unroll
        for (int i = 0; i < 16; ++i) {
            double diff = r[i] - (double)c[i];
            d = fma(diff, diff, d);
        }
        int idx = tid;
        #pragma unroll
        for (int sft = 32; sft > 0; sft >>= 1) {
            double d2 = __shfl_down(d, sft, 64);
            int i2 = __shfl_down(idx, sft, 64);
            if (d2 < d || (d2 == d && i2 < idx)) { d = d2; idx = i2; }
        }
        if (lane == 0) { wd_s[wv] = d; wi_s[wv] = idx; }
        __syncthreads();
        if (tid == 0) {
            double bd_ = wd_s[0]; int bi = wi_s[0];
            #pragma unroll
            for (int w = 1; w < 4; ++w) {
                if (wd_s[w] < bd_ || (wd_s[w] == bd_ && wi_s[w] < bi)) {
                    bd_ = wd_s[w]; bi = wi_s[w];
                }
            }
            best_s = bi;
            out_idx[(size_t)q * NPOS + pos] = (float)bi;
        }
        __syncthreads();
        int best = best_s;
        if (tid < 16)
            r[tid] = r[tid] - (double)cb[((size_t)(q * KCB) + best) * 16 + tid];
        __syncthreads();
    }
}

// ---------------- host launcher ----------------
extern "C" void kernel_launch(void* const* d_in, const int* in_sizes, int n_in,
                              void* d_out, int out_size, void* d_ws, size_t ws_size,
                              hipStream_t stream) {
    const float* mel = (const float*)d_in[0];
    const float* w1  = (const float*)d_in[1];
    const float* b1  = (const float*)d_in[2];
    const float* g1  = (const float*)d_in[3];
    const float* be1 = (const float*)d_in[4];
    const float* m1  = (const float*)d_in[5];
    const float* v1  = (const float*)d_in[6];
    const float* w2  = (const float*)d_in[7];
    const float* b2  = (const float*)d_in[8];
    const float* g2  = (const float*)d_in[9];
    const float* be2 = (const float*)d_in[10];
    const float* m2  = (const float*)d_in[11];
    const float* v2  = (const float*)d_in[12];
    const float* wd  = (const float*)d_in[13];
    const float* bd  = (const float*)d_in[14];
    const float* wp  = (const float*)d_in[15];
    const float* bp  = (const float*)d_in[16];
    const float* cb  = (const float*)d_in[17];

    const int nb = 8;                  // batches per group
    const int ngrp = B_ / nb;          // 2
    const int nsplit = 16;
    const int cis = 256 / nsplit;

    const size_t x1_bytes = (size_t)nb * C_ * T_ * 8;   // 67,108,864 (shared w/ parts)
    const size_t x2_bytes = (size_t)nb * C_ * T_ * 8;   // 67,108,864
    const size_t zd_bytes = (size_t)B_ * TP * 16 * 8;   // 698,368

    // tier A: f64 weight tables; tier B: f32 tables + in-kernel cvt
    const size_t needA = x1_bytes + x2_bytes + (size_t)80*5*256*8
                       + (size_t)256*5*256*8 + (size_t)256*24*128*4
                       + 4*2048 + zd_bytes + 8192;      // ~139.95 MB
    const bool tierA = (ws_size >= needA);

    char* ws = (char*)d_ws;
    size_t off = 0;
    auto alloc = [&](size_t bytes) -> char* {
        char* p = ws + off;
        off = (off + bytes + 255) & ~(size_t)255;
        return p;
    };
    char* shared = alloc(x1_bytes);
    double* x1d  = (double*)shared;     // dead when convd runs
    double* parts= (double*)shared;     // aliases x1; parts[0] becomes e (f64)
    double* x2d  = (double*)alloc(x2_bytes);
    void*   w1t  = (void*)alloc(tierA ? (size_t)80*5*256*8  : (size_t)80*5*256*4);
    void*   w2t  = (void*)alloc(tierA ? (size_t)256*5*256*8 : (size_t)256*5*256*4);
    float*  wdt  = (float*)alloc((size_t)256*24*128*4);
    double* a1d  = (double*)alloc(2048);
    double* bt1d = (double*)alloc(2048);
    double* a2d  = (double*)alloc(2048);
    double* bt2d = (double*)alloc(2048);
    double* zd   = (double*)alloc(zd_bytes);

    float* e_out   = (float*)d_out;                          // [16][128][341]
    float* idx_out = (float*)d_out + (size_t)B_ * EMB * TP;  // [8][16][341]

    prep_common<<<3072, 256, 0, stream>>>(wd, b1, g1, be1, m1, v1,
                                          b2, g2, be2, m2, v2,
                                          wdt, a1d, bt1d, a2d, bt2d);
    if (tierA)
        prep_wf64<<<1280, 256, 0, stream>>>(w1, w2, (double*)w1t, (double*)w2t);
    else
        prep_wf32<<<1280, 256, 0, stream>>>(w1, w2, (float*)w1t, (float*)w2t);

    const int comb_blocks = (nb * EMB * TP + 255) / 256;
    for (int g = 0; g < ngrp; ++g) {
        const float* mel_g = mel + (size_t)(g * nb) * CIN1 * T_;
        if (tierA) {
            conv5_v10<CIN1, float, double><<<dim3(4, 32, nb), 256, 0, stream>>>(
                mel_g, (const double*)w1t, a1d, bt1d, x1d);
            conv5_v10<C_, double, double><<<dim3(4, 32, nb), 256, 0, stream>>>(
                x1d, (const double*)w2t, a2d, bt2d, x2d);
        } else {
            conv5_v10<CIN1, float, float><<<dim3(4, 32, nb), 256, 0, stream>>>(
                mel_g, (const float*)w1t, a1d, bt1d, x1d);
            conv5_v10<C_, double, float><<<dim3(4, 32, nb), 256, 0, stream>>>(
                x1d, (const float*)w2t, a2d, bt2d, x2d);
        }
        // x1 dead from here -> parts may reuse it
        convd_f64_v7<<<dim3(3, 1, nb * nsplit), 256, 0, stream>>>(
            x2d, wdt, parts, nb, nsplit, cis);
        convd_combine<<<comb_blocks, 256, 0, stream>>>(
            parts, bd, e_out, nb, g * nb, nsplit);
        zproj_f64<<<dim3(3, nb), 128, 0, stream>>>(
            parts, wp, bp, zd + (size_t)g * nb * TP * 16);
    }
    rvq_f64_v2<<<NPOS, 256, 0, stream>>>(zd, cb, idx_out);
}